// Round 1
// baseline (266.935 us; speedup 1.0000x reference)
//
#include <hip/hip_runtime.h>
#include <stdint.h>

// Preprocess: bilinear 1024->256 (exact 2x2 avg since scale=4) + reflect-pad
// 30 + 127-tap separable Gaussian (zero-padded conv on 316x316) + crop.
// fp32 in/out. fp16 H intermediate in ws.
//
// R6: K1 is wave-autonomous (ZERO barriers): each wave owns one padded row:
//   load 2 input rows (coalesced) -> resize -> wave-private LDS row (zeros +
//   reflect borders, in-order DS pipe, no sync) -> 127-tap h-blur (zero-padded
//   sliding float4 weights) -> fp16 store. Weights per-wave with analytic
//   normalizer 1/S (S = 44.69106, exact to ~1e-4 rel; output effect ~1e-5).
// K2: 64x64 tile v-blur (1 barrier for the tile), same per-wave weights.
// R7: vblur inner loop uses v_pk_fma_f32 (packed dual-f32 FMA) via inline asm:
//   64 scalar fmac/iter -> 32 pk_fma + 4 weight dups. hblur untouched (it is
//   fetch-bound at ~16us: 100.7MB mandatory input traffic).

#define CHTOT 48
#define IN_W  1024
#define OUT_W 256
#define PADW  316
#define KTAP  127
#define INV_S 0.02237584f   // 1 / sum_{x=-63..63} 2^(-(x/21)^2)

typedef _Float16 half_t;
typedef __attribute__((ext_vector_type(4))) _Float16 half4;
typedef __attribute__((ext_vector_type(2))) float f2;

__device__ __forceinline__ float4 h2f4(half4 h) {
    return make_float4((float)h.x, (float)h.y, (float)h.z, (float)h.w);
}

// Packed dual-FMA: a = v * w + a on both 32-bit halves (VOP3P, gfx90a+).
__device__ __forceinline__ void pkfma(f2& a, f2 v, f2 w) {
    asm("v_pk_fma_f32 %0, %1, %2, %0" : "+v"(a) : "v"(v), "v"(w));
}

// Fill this wave's 136-slot zero-padded normalized weight row. No barrier.
__device__ __forceinline__ void wave_weights(float* W, int l) {
    float q0 = (float)(l - 63) * (1.0f / 21.0f);          // t = l (3..66)
    W[3 + l] = exp2f(-q0 * q0) * INV_S;
    if (l < 63) {                                          // t = l+64 (67..129)
        float q1 = (float)(l + 1) * (1.0f / 21.0f);
        W[67 + l] = exp2f(-q1 * q1) * INV_S;
    }
    if (l < 3) W[l] = 0.f;                                 // slots 0..2
    if (l >= 58) W[72 + l] = 0.f;                          // slots 130..135
}

__global__ __launch_bounds__(256) void hblur_kernel(const float* __restrict__ in,
                                                    half_t* __restrict__ H) {
    __shared__ float Wp[4][136];     // per-wave weights (544 B each, 16B-aligned)
    __shared__ float Rw[4][384];     // per-wave extended row
    const int tid = threadIdx.x;
    const int w = tid >> 6, l = tid & 63;
    float* W = Wp[w];
    wave_weights(W, l);

    const int ch = blockIdx.y;
    const int p = blockIdx.x * 4 + w;            // padded row 0..315 (79*4=316)
    const float4* in4 = (const float4*)(in + (size_t)ch * (IN_W * IN_W));

    // ---- resize this row: cols l, l+64, l+128, l+192 ----
    int pp = p - 30;
    int r = pp < 0 ? -pp : (pp > 255 ? 510 - pp : pp);     // reflect rows
    const float4* row1 = in4 + (4 * r + 1) * (IN_W / 4);
    const float4* row2 = row1 + (IN_W / 4);
    float* Rx = Rw[w];
    #pragma unroll
    for (int k = 0; k < 4; ++k) {
        float4 a = row1[l + 64 * k];
        float4 b = row2[l + 64 * k];
        float m1 = 0.5f * a.y + 0.5f * b.y;                // axis2 (rows) first
        float m2 = 0.5f * a.z + 0.5f * b.z;
        Rx[63 + l + 64 * k] = 0.5f * m1 + 0.5f * m2;       // then axis3
    }
    // ---- borders (within-wave; DS pipe is in-order, no barrier) ----
    if (l < 33)      Rx[l] = 0.f;                          // left zeros 0..32
    else if (l < 63) Rx[l] = Rx[126 - l];                  // left mirror 33..62
    {
        int e = 319 + l;                                   // 319..382
        float v = (e < 349) ? Rx[636 - e] : 0.f;           // right mirror/zeros
        Rx[e] = v;
        if (l == 63) Rx[383] = 0.f;
    }

    // ---- 127-tap h-blur: out cols 4l..4l+3 ----
    const float4* Rv = (const float4*)Rx;
    const float4* W4 = (const float4*)W;
    float acc0 = 0.f, acc1 = 0.f, acc2 = 0.f, acc3 = 0.f;
    float4 wlo = W4[0];
    #pragma unroll
    for (int i = 0; i < 33; ++i) {
        float4 whi = W4[i + 1];
        float4 v = Rv[l + i];
        acc0 = fmaf(v.x, wlo.w, acc0); acc0 = fmaf(v.y, whi.x, acc0);
        acc0 = fmaf(v.z, whi.y, acc0); acc0 = fmaf(v.w, whi.z, acc0);
        acc1 = fmaf(v.x, wlo.z, acc1); acc1 = fmaf(v.y, wlo.w, acc1);
        acc1 = fmaf(v.z, whi.x, acc1); acc1 = fmaf(v.w, whi.y, acc1);
        acc2 = fmaf(v.x, wlo.y, acc2); acc2 = fmaf(v.y, wlo.z, acc2);
        acc2 = fmaf(v.z, wlo.w, acc2); acc2 = fmaf(v.w, whi.x, acc2);
        acc3 = fmaf(v.x, wlo.x, acc3); acc3 = fmaf(v.y, wlo.y, acc3);
        acc3 = fmaf(v.z, wlo.z, acc3); acc3 = fmaf(v.w, wlo.w, acc3);
        wlo = whi;
    }
    half4 hv;
    hv.x = (half_t)acc0; hv.y = (half_t)acc1;
    hv.z = (half_t)acc2; hv.w = (half_t)acc3;
    ((half4*)H)[((size_t)ch * PADW + p) * 64 + l] = hv;
}

__global__ __launch_bounds__(256) void vblur_kernel(const half_t* __restrict__ H,
                                                    float* __restrict__ out) {
    __shared__ float  Wp[4][136];
    __shared__ float4 T[192 * 16];               // 192 rows x 64 fp32 cols
    const int tid = threadIdx.x;
    const int w = tid >> 6, l = tid & 63;
    wave_weights(Wp[w], l);

    const int ch = blockIdx.y;
    const int xt = blockIdx.x & 3;
    const int yt = blockIdx.x >> 2;
    const int x0h4 = xt * 16;
    const int y0 = yt * 64;

    const half4* H4 = (const half4*)H;
    for (int idx = tid; idx < 192 * 16; idx += 256) {
        int rr = idx >> 4, fx = idx & 15;
        int r = y0 - 33 + rr;                    // zero outside [0,316)
        float4 v = make_float4(0.f, 0.f, 0.f, 0.f);
        if (r >= 0 && r < PADW) v = h2f4(H4[((size_t)ch * PADW + r) * 64 + x0h4 + fx]);
        T[idx] = v;
    }
    __syncthreads();

    const float4* W4 = (const float4*)Wp[w];
    int cg = tid & 15;
    int g  = tid >> 4;                           // output rows 4g..4g+3
    f2 z = {0.f, 0.f};
    f2 a0l = z, a0h = z, a1l = z, a1h = z;
    f2 a2l = z, a2h = z, a3l = z, a3h = z;
    float4 wlo4 = W4[0];
    f2 wl0 = {wlo4.x, wlo4.x}, wl1 = {wlo4.y, wlo4.y};
    f2 wl2 = {wlo4.z, wlo4.z}, wl3 = {wlo4.w, wlo4.w};
    #pragma unroll
    for (int i = 0; i < 33; ++i) {
        float4 whi4 = W4[i + 1];
        f2 wh0 = {whi4.x, whi4.x}, wh1 = {whi4.y, whi4.y};
        f2 wh2 = {whi4.z, whi4.z}, wh3 = {whi4.w, whi4.w};
        int base = (4 * g + 4 * i) * 16 + cg;    // max T row 191
        float4 v0 = T[base];
        float4 v1 = T[base + 16];
        float4 v2 = T[base + 32];
        float4 v3 = T[base + 48];
        f2 v0l = {v0.x, v0.y}, v0h = {v0.z, v0.w};
        f2 v1l = {v1.x, v1.y}, v1h = {v1.z, v1.w};
        f2 v2l = {v2.x, v2.y}, v2h = {v2.z, v2.w};
        f2 v3l = {v3.x, v3.y}, v3h = {v3.z, v3.w};
        // acc0: v0*wl3, v1*wh0, v2*wh1, v3*wh2
        pkfma(a0l, v0l, wl3); pkfma(a0h, v0h, wl3);
        pkfma(a0l, v1l, wh0); pkfma(a0h, v1h, wh0);
        pkfma(a0l, v2l, wh1); pkfma(a0h, v2h, wh1);
        pkfma(a0l, v3l, wh2); pkfma(a0h, v3h, wh2);
        // acc1: v0*wl2, v1*wl3, v2*wh0, v3*wh1
        pkfma(a1l, v0l, wl2); pkfma(a1h, v0h, wl2);
        pkfma(a1l, v1l, wl3); pkfma(a1h, v1h, wl3);
        pkfma(a1l, v2l, wh0); pkfma(a1h, v2h, wh0);
        pkfma(a1l, v3l, wh1); pkfma(a1h, v3h, wh1);
        // acc2: v0*wl1, v1*wl2, v2*wl3, v3*wh0
        pkfma(a2l, v0l, wl1); pkfma(a2h, v0h, wl1);
        pkfma(a2l, v1l, wl2); pkfma(a2h, v1h, wl2);
        pkfma(a2l, v2l, wl3); pkfma(a2h, v2h, wl3);
        pkfma(a2l, v3l, wh0); pkfma(a2h, v3h, wh0);
        // acc3: v0*wl0, v1*wl1, v2*wl2, v3*wl3
        pkfma(a3l, v0l, wl0); pkfma(a3h, v0h, wl0);
        pkfma(a3l, v1l, wl1); pkfma(a3h, v1h, wl1);
        pkfma(a3l, v2l, wl2); pkfma(a3h, v2h, wl2);
        pkfma(a3l, v3l, wl3); pkfma(a3h, v3h, wl3);
        wl0 = wh0; wl1 = wh1; wl2 = wh2; wl3 = wh3;
    }

    float4* o4 = (float4*)out;
    float4 accs[4] = {
        make_float4(a0l.x, a0l.y, a0h.x, a0h.y),
        make_float4(a1l.x, a1l.y, a1h.x, a1h.y),
        make_float4(a2l.x, a2l.y, a2h.x, a2h.y),
        make_float4(a3l.x, a3l.y, a3h.x, a3h.y)
    };
    #pragma unroll
    for (int j = 0; j < 4; ++j) {
        int y = y0 + 4 * g + j;
        o4[((size_t)ch * OUT_W + y) * 64 + xt * 16 + cg] = accs[j];
    }
}

extern "C" void kernel_launch(void* const* d_in, const int* in_sizes, int n_in,
                              void* d_out, int out_size, void* d_ws, size_t ws_size,
                              hipStream_t stream) {
    const float* in = (const float*)d_in[0];
    float* out = (float*)d_out;
    half_t* H = (half_t*)d_ws;                   // 48*316*256 fp16 = 7.8 MB

    hblur_kernel<<<dim3(79, CHTOT), dim3(256), 0, stream>>>(in, H);
    vblur_kernel<<<dim3(16, CHTOT), dim3(256), 0, stream>>>(H, out);
}